// Round 24
// baseline (52.361 us; speedup 1.0000x reference)
//
#include <hip/hip_runtime.h>

// Depthwise xcorr: out[p][oy][ox] = sum_{ky,kx} x[p][oy+ky][ox+kx] * z[p][ky][kx]
// 32768 planes. x: 31x31, z: 7x7, out: 25x25, fp32.
//
// Round 24: cut the LDS pipe (the measured 30us/CU wall) via LINEAR
// conflict-free layout instead of XOR swizzle:
//  - x row stride 37 (5 mod 32): banks = 5ty+tx -> 25 distinct lanes/plane
//    with NO xor; reads pb[iy*37+k] are consecutive -> compiler merges into
//    ds_read2_b32 (xor blocked all merging; that was R15/R23's hidden cost).
//  - plane stride 1156 (4 mod 32): 3 coresident planes de-aliased (<=3-way).
//  - z in 52-stride planes, read as 12xb128+1 (R22-proven, incl dword-aligned
//    16B global_load_lds source). 285 -> 156 cyc/wave.
//  - staging: 4B global_load_lds (37-stride chunks not 16B-contiguous);
//    incremental p/rem + magic div37 per chunk; fast path needs NO clamps
//    (pad rows/cols source valid neighbor data, never read).
// 128 thr, PPB=5 (125/128), LDS 25088 B -> 6 blocks/CU, one-shot grid.

#define PPB 5
#define WX 31
#define XPLANE 961
#define TDW (PPB * XPLANE)     // 4805
#define RS 37                  // LDS row stride (5 mod 32)
#define PSTR 1156              // LDS plane stride (4 mod 32), >= 31*37=1147
#define XDW (PPB * PSTR)       // 5780
#define XCH 46                 // ceil(5780/128)
#define XALLOC (XCH * 128)     // 5888 (overhang slots 5780..5887 = pad)
#define ZSTR 52
#define ZB XALLOC              // z region base dword (5888, 16B-aligned)
#define ZPLANE 49
#define ZDW (PPB * ZPLANE)     // 245
#define ZALLOC 384             // 3*128 (tail staging range)
#define OPLANE 625
#define WO 25

typedef __attribute__((address_space(1))) const void gaddr_t;
typedef __attribute__((address_space(3))) void laddr_t;

__global__ __launch_bounds__(128, 2) void dwxcorr_kernel(
    const float* __restrict__ z, const float* __restrict__ x,
    float* __restrict__ out, int nplanes) {
  __shared__ float lds[XALLOC + ZALLOC];  // 25088 B -> 6 blocks/CU

  const int tid = threadIdx.x;
  const int t = blockIdx.x;
  const int wb1 = tid & ~63;         // wave-uniform dword base (4B/lane)
  const int wb4 = (tid & ~63) * 4;   // wave-uniform dword base (16B/lane)
  const long XTOT = (long)nplanes * XPLANE;
  const long ZTOT = (long)nplanes * ZPLANE;
  const long xoff = (long)t * TDW;
  const long zoff = (long)t * ZDW;
  const int p0 = t * PPB;
  const int pmax = min(PPB, nplanes - p0);

  // LDS dword (p, row, col) = x[p*961 + row*31 + col], row stride 37
  if (p0 + PPB < nplanes) {
    // ---- fast path (6553/6554 blocks): zero clamps ----
    int p = 0, rem = tid;            // s = c*128+tid; p = s/PSTR, rem = s%PSTR
#pragma unroll
    for (int c = 0; c < XCH; ++c) {
      int row = rem / RS;            // 0..31 (31 = pad, sources next plane)
      int col = rem - row * RS;      // 0..36 (31..36 pad, sources next row)
      long g = xoff + (long)p * XPLANE + row * WX + col;  // always in-bounds
      __builtin_amdgcn_global_load_lds((gaddr_t*)(x + g),
                                       (laddr_t*)&lds[c * 128 + wb1], 4, 0, 0);
      rem += 128;
      if (rem >= PSTR) { rem -= PSTR; ++p; }
    }
    if (tid < 65) {                  // z: 260 dwords as 16B chunks
      int s4 = tid * 4;
      int zp = s4 / ZSTR;
      int zc = s4 - zp * ZSTR;       // cols 49..51 source next plane (unread)
      long g = zoff + (long)zp * ZPLANE + zc;
      __builtin_amdgcn_global_load_lds((gaddr_t*)(z + g),
                                       (laddr_t*)&lds[ZB + wb4], 16, 0, 0);
    }
  } else {
    // ---- tail block (last): 4B staging, everything clamped ----
#pragma unroll
    for (int c = 0; c < XCH; ++c) {
      int s = c * 128 + tid;
      int p = s / PSTR;
      int r = s - p * PSTR;
      int row = r / RS;
      int col = r - row * RS;
      if (p >= pmax) p = pmax - 1;
      if (row > 30) row = 30;
      if (col > 30) col = 30;
      long g = xoff + (long)p * XPLANE + row * WX + col;
      if (g > XTOT - 1) g = XTOT - 1;
      __builtin_amdgcn_global_load_lds((gaddr_t*)(x + g),
                                       (laddr_t*)&lds[c * 128 + wb1], 4, 0, 0);
    }
#pragma unroll
    for (int c = 0; c < 3; ++c) {
      int s = c * 128 + tid;
      int ss = (s > 259) ? 259 : s;  // dest auto = slot s (pad), source dup
      int zp = ss / ZSTR;
      int zc = ss - zp * ZSTR;
      if (zp >= pmax) zp = pmax - 1;
      if (zc > 48) zc = 48;
      long g = zoff + (long)zp * ZPLANE + zc;
      if (g > ZTOT - 1) g = ZTOT - 1;
      __builtin_amdgcn_global_load_lds((gaddr_t*)(z + g),
                                       (laddr_t*)&lds[ZB + c * 128 + wb1],
                                       4, 0, 0);
    }
  }
  __syncthreads();  // single drain + barrier

  // ---- compute: thread -> (plane cpp, 5x5 tile (ty,tx)); 125/128 active ----
  const int cpp = tid / 25;
  if (tid >= PPB * 25 || cpp >= pmax) return;
  const int t25 = tid - cpp * 25;
  const int ty = t25 / 5;
  const int tx = t25 - ty * 5;
  const int tx5 = tx * 5;

  // z -> 49 regs via 12 x b128 + 1 b32 (16B-aligned: ZB, ZSTR mult of 4)
  const float* zl = &lds[ZB + ZSTR * cpp];
  float zr[ZPLANE];
#pragma unroll
  for (int i = 0; i < 12; ++i) {
    float4 v = *(const float4*)(zl + 4 * i);
    zr[4 * i + 0] = v.x; zr[4 * i + 1] = v.y;
    zr[4 * i + 2] = v.z; zr[4 * i + 3] = v.w;
  }
  zr[48] = zl[48];

  float acc[5][5];
#pragma unroll
  for (int r = 0; r < 5; ++r)
#pragma unroll
    for (int j = 0; j < 5; ++j) acc[r][j] = 0.0f;

  const float* pb = &lds[cpp * PSTR + (ty * 5) * RS + tx5];

  // Stream 11 patch rows; LINEAR consecutive reads (merge into ds_read2_b32)
#pragma unroll
  for (int iy = 0; iy < 11; ++iy) {
    float xr[11];
#pragma unroll
    for (int k = 0; k < 11; ++k) xr[k] = pb[iy * RS + k];
    const int ky_lo = (iy - 4 < 0) ? 0 : iy - 4;
    const int ky_hi = (iy < 6) ? iy : 6;
#pragma unroll
    for (int ky = 0; ky < 7; ++ky) {
      if (ky < ky_lo || ky > ky_hi) continue;  // folds at compile time
      const int orow = iy - ky;
#pragma unroll
      for (int kx = 0; kx < 7; ++kx) {
        const float zv = zr[ky * 7 + kx];
#pragma unroll
        for (int j = 0; j < 5; ++j)
          acc[orow][j] = fmaf(xr[kx + j], zv, acc[orow][j]);
      }
    }
  }

  // ---- write the 5x5 tile ----
  float* ob = out + (long)(p0 + cpp) * OPLANE + (ty * 5) * WO + tx5;
#pragma unroll
  for (int r = 0; r < 5; ++r)
#pragma unroll
    for (int j = 0; j < 5; ++j) ob[r * WO + j] = acc[r][j];
}

extern "C" void kernel_launch(void* const* d_in, const int* in_sizes, int n_in,
                              void* d_out, int out_size, void* d_ws, size_t ws_size,
                              hipStream_t stream) {
  const float* z = (const float*)d_in[0];  // [B,C,7,7]
  const float* x = (const float*)d_in[1];  // [B,C,31,31]
  float* out = (float*)d_out;              // [B,C,25,25]

  const int nplanes = in_sizes[0] / ZPLANE;      // 32768
  const int blocks = (nplanes + PPB - 1) / PPB;  // 6554

  hipLaunchKernelGGL(dwxcorr_kernel, dim3(blocks), dim3(128), 0, stream,
                     z, x, out, nplanes);
}

// Round 25
// 51.671 us; speedup vs baseline: 1.0133x; 1.0133x over previous
//
#include <hip/hip_runtime.h>

// Depthwise xcorr: out[p][oy][ox] = sum_{ky,kx} x[p][oy+ky][ox+kx] * z[p][ky][kx]
// 32768 planes. x: 31x31, z: 7x7, out: 25x25, fp32.
//
// Round 25: RS=36 — the stride that satisfies all three constraints at once:
//  - banks: (row*36+col) mod 32 = 4row+5tx+k -> 25 lanes/plane have only 4
//    two-way aliases (free), NO xor swizzle;
//  - 16B staging: 36 = 9 chunks of 4 -> every 16B LDS chunk = 4 contiguous
//    global dwords (pad cols source next row, valid memory; final tile uses
//    4B clamped path);
//  - linear reads pb[iy*36+k] -> compiler merges to ds_read2_b32 (~66 LDS
//    instr vs 121).
// Plane stride 1116 (28 mod 32) de-aliases the 3 coresident planes. z via
// ZSTR=52 planes read as 12xb128+1 (R22/R24-proven; 13 ops vs 49).
// LDS = 23360 B -> 7 blocks/CU (163520 <= 163840). Else identical to R15.

#define PPB 5
#define WX 31
#define XPLANE 961
#define TDW (PPB * XPLANE)     // 4805
#define RS 36                  // LDS row stride (4 mod 32), 9 chunks of 4
#define PSTR (31 * RS)         // 1116 (28 mod 32)
#define XDW (PPB * PSTR)       // 5580
#define ZB XDW                 // z region base dword (5580, 16B-aligned)
#define ZSTR 52                // z plane stride (13 chunks of 4)
#define ZPLANE 49
#define ZDW (PPB * ZPLANE)     // 245
#define ZREGION 260            // 5*52
#define OPLANE 625
#define WO 25

typedef __attribute__((address_space(1))) const void gaddr_t;
typedef __attribute__((address_space(3))) void laddr_t;

__global__ __launch_bounds__(128, 2) void dwxcorr_kernel(
    const float* __restrict__ z, const float* __restrict__ x,
    float* __restrict__ out, int nplanes) {
  __shared__ float lds[XDW + ZREGION];  // 5840 dwords = 23360 B -> 7 blocks/CU

  const int tid = threadIdx.x;
  const int t = blockIdx.x;
  const int wb4 = (tid & ~63) * 4;   // wave-uniform dword base (16B/lane)
  const int wb1 = tid & ~63;         // wave-uniform dword base (4B/lane)
  const long XTOT = (long)nplanes * XPLANE;
  const long ZTOT = (long)nplanes * ZPLANE;
  const long xoff = (long)t * TDW;
  const long zoff = (long)t * ZDW;
  const int p0 = t * PPB;
  const int pmax = min(PPB, nplanes - p0);

  // LDS dword (p, row, col) = x[p*961 + row*31 + col] (row stride 36;
  // pad cols 31..35 source next row = valid memory, never read)
  if (p0 + PPB < nplanes) {
    // ---- fast path (6553/6554 blocks): 16B chunks, zero clamps ----
#pragma unroll
    for (int c = 0; c < 11; ++c) {
      if (c < 10 || tid < 115) {       // chunk 10 partial: slots 5120..5579
        int s = c * 512 + tid * 4;     // 4-aligned LDS slot
        int p = s / PSTR;              // magic-mul div
        int r = s - p * PSTR;
        int row = r / RS;              // 0..30
        int col = r - row * RS;        // 4-aligned, 0..32
        long g = xoff + (long)p * XPLANE + row * WX + col;  // in-bounds
        __builtin_amdgcn_global_load_lds((gaddr_t*)(x + g),
                                         (laddr_t*)&lds[c * 512 + wb4],
                                         16, 0, 0);
      }
    }
    if (tid < 65) {                    // z: slots 0..259 of z region
      int s4 = tid * 4;
      int zp = s4 / ZSTR;
      int zc = s4 - zp * ZSTR;         // chunks never cross a 52-boundary
      long g = zoff + (long)zp * ZPLANE + zc;  // pads source next plane
      __builtin_amdgcn_global_load_lds((gaddr_t*)(z + g),
                                       (laddr_t*)&lds[ZB + wb4], 16, 0, 0);
    }
  } else {
    // ---- tail block (last): 4B staging, per-dword clamps ----
#pragma unroll
    for (int c = 0; c < 44; ++c) {
      int s = c * 128 + tid;
      if (s < XDW) {
        int p = s / PSTR;
        int r = s - p * PSTR;
        int row = r / RS;
        int col = r - row * RS;
        if (p >= pmax) p = pmax - 1;   // dup, never read
        if (col > 30) col = 30;
        long g = xoff + (long)p * XPLANE + row * WX + col;
        if (g > XTOT - 1) g = XTOT - 1;
        __builtin_amdgcn_global_load_lds((gaddr_t*)(x + g),
                                         (laddr_t*)&lds[c * 128 + wb1], 4, 0, 0);
      }
    }
#pragma unroll
    for (int c = 0; c < 2; ++c) {      // z slots 0..255
      int s = c * 128 + tid;
      int zp = s / ZSTR;
      int zc = s - zp * ZSTR;
      if (zp >= pmax) zp = pmax - 1;
      if (zc > 48) zc = 48;
      long g = zoff + (long)zp * ZPLANE + zc;
      if (g > ZTOT - 1) g = ZTOT - 1;
      __builtin_amdgcn_global_load_lds((gaddr_t*)(z + g),
                                       (laddr_t*)&lds[ZB + c * 128 + wb1],
                                       4, 0, 0);
    }
    if (tid < 4) {                     // z slots 256..259
      int s = 256 + tid;
      int zp = s / ZSTR;               // 4
      int zc = s - zp * ZSTR;          // 48..51
      if (zp >= pmax) zp = pmax - 1;
      if (zc > 48) zc = 48;
      long g = zoff + (long)zp * ZPLANE + zc;
      if (g > ZTOT - 1) g = ZTOT - 1;
      __builtin_amdgcn_global_load_lds((gaddr_t*)(z + g),
                                       (laddr_t*)&lds[ZB + 256 + wb1], 4, 0, 0);
    }
  }
  __syncthreads();  // single drain + barrier

  // ---- compute: thread -> (plane cpp, 5x5 tile (ty,tx)); 125/128 active ----
  const int cpp = tid / 25;
  if (tid >= PPB * 25 || cpp >= pmax) return;
  const int t25 = tid - cpp * 25;
  const int ty = t25 / 5;
  const int tx = t25 - ty * 5;
  const int tx5 = tx * 5;

  // z -> 49 regs via 12 x b128 + 1 b32 (broadcast per plane group)
  const float* zl = &lds[ZB + cpp * ZSTR];
  float zr[ZPLANE];
#pragma unroll
  for (int i = 0; i < 12; ++i) {
    float4 v = *(const float4*)(zl + 4 * i);
    zr[4 * i + 0] = v.x; zr[4 * i + 1] = v.y;
    zr[4 * i + 2] = v.z; zr[4 * i + 3] = v.w;
  }
  zr[48] = zl[48];

  float acc[5][5];
#pragma unroll
  for (int r = 0; r < 5; ++r)
#pragma unroll
    for (int j = 0; j < 5; ++j) acc[r][j] = 0.0f;

  const float* pb = &lds[cpp * PSTR + (ty * 5) * RS + tx5];

  // Stream 11 patch rows; LINEAR reads (merge to ds_read2_b32), <=2-way banks
#pragma unroll
  for (int iy = 0; iy < 11; ++iy) {
    float xr[11];
#pragma unroll
    for (int k = 0; k < 11; ++k) xr[k] = pb[iy * RS + k];
    const int ky_lo = (iy - 4 < 0) ? 0 : iy - 4;
    const int ky_hi = (iy < 6) ? iy : 6;
#pragma unroll
    for (int ky = 0; ky < 7; ++ky) {
      if (ky < ky_lo || ky > ky_hi) continue;  // folds at compile time
      const int orow = iy - ky;
#pragma unroll
      for (int kx = 0; kx < 7; ++kx) {
        const float zv = zr[ky * 7 + kx];
#pragma unroll
        for (int j = 0; j < 5; ++j)
          acc[orow][j] = fmaf(xr[kx + j], zv, acc[orow][j]);
      }
    }
  }

  // ---- write the 5x5 tile ----
  float* ob = out + (long)(p0 + cpp) * OPLANE + (ty * 5) * WO + tx5;
#pragma unroll
  for (int r = 0; r < 5; ++r)
#pragma unroll
    for (int j = 0; j < 5; ++j) ob[r * WO + j] = acc[r][j];
}

extern "C" void kernel_launch(void* const* d_in, const int* in_sizes, int n_in,
                              void* d_out, int out_size, void* d_ws, size_t ws_size,
                              hipStream_t stream) {
  const float* z = (const float*)d_in[0];  // [B,C,7,7]
  const float* x = (const float*)d_in[1];  // [B,C,31,31]
  float* out = (float*)d_out;              // [B,C,25,25]

  const int nplanes = in_sizes[0] / ZPLANE;      // 32768
  const int blocks = (nplanes + PPB - 1) / PPB;  // 6554

  hipLaunchKernelGGL(dwxcorr_kernel, dim3(blocks), dim3(128), 0, stream,
                     z, x, out, nplanes);
}